// Round 6
// baseline (224.388 us; speedup 1.0000x reference)
//
#include <hip/hip_runtime.h>
#include <hip/hip_fp16.h>

#define DD 300
#define KK 50
#define BB 32
#define SS 8192
#define NN 128
#define LL 64
#define NSEG (BB * NN)   // 4096
#define NW 5             // waves per block (k_y / k_rest)
#define NT 320           // threads per block
#define NJ 13            // rows per wave = ceil(64/5)
#define TM 8             // segments per k_u block

__device__ __forceinline__ float wave_sum(float v) {
    #pragma unroll
    for (int m = 32; m; m >>= 1) v += __shfl_xor(v, m, 64);
    return v;
}
__device__ __forceinline__ float wave_max(float v) {
    #pragma unroll
    for (int m = 32; m; m >>= 1) v = fmaxf(v, __shfl_xor(v, m, 64));
    return v;
}
__device__ __forceinline__ unsigned int pack_h2(float a, float b) {
    __half2 h = __floats2half2_rn(a, b);
    return *reinterpret_cast<const unsigned int*>(&h);
}
__device__ __forceinline__ float2 unpack_h2(unsigned int v) {
    __half2 h = *reinterpret_cast<const __half2*>(&v);
    return __half22float2(h);
}

// ============ K1: y = masked mean — float4 branch-free gather ============
__global__ __launch_bounds__(NT) void k_y(
    const float* __restrict__ emb,
    const int*   __restrict__ tokens,
    const int*   __restrict__ seg_starts,
    const int*   __restrict__ seg_lens,
    float* __restrict__ out_y)
{
    __shared__ int    tok_s[LL];
    __shared__ float4 part4[NW][75];      // 6 KB

    const int tid  = threadIdx.x;
    const int wave = tid >> 6;
    const int lane = tid & 63;
    const int seg  = blockIdx.x;
    const int b    = seg >> 7;            // N = 128
    const int start = seg_starts[seg];
    const int len   = seg_lens[seg];

    if (tid < LL) tok_s[tid] = tokens[b * SS + start + tid];
    __syncthreads();

    float4 a0 = {0.f, 0.f, 0.f, 0.f};
    float4 a1 = {0.f, 0.f, 0.f, 0.f};
    #pragma unroll
    for (int j = 0; j < NJ; ++j) {
        const int l  = wave + j * NW;
        const int lc = (l < len) ? l : (len - 1);
        const float4* row4 = (const float4*)(emb + (size_t)tok_s[lc] * DD);
        const float4 r0 = row4[lane];
        float4 r1 = {0.f, 0.f, 0.f, 0.f};
        if (lane < 11) r1 = row4[64 + lane];
        const float m = (l < len) ? 1.f : 0.f;
        a0.x += m * r0.x; a0.y += m * r0.y; a0.z += m * r0.z; a0.w += m * r0.w;
        a1.x += m * r1.x; a1.y += m * r1.y; a1.z += m * r1.z; a1.w += m * r1.w;
    }
    part4[wave][lane] = a0;
    if (lane < 11) part4[wave][64 + lane] = a1;
    __syncthreads();

    if (tid < 75) {
        float4 s = {0.f, 0.f, 0.f, 0.f};
        #pragma unroll
        for (int w = 0; w < NW; ++w) {
            const float4 pv = part4[w][tid];
            s.x += pv.x; s.y += pv.y; s.z += pv.z; s.w += pv.w;
        }
        const float inv = 1.f / (float)len;
        s.x *= inv; s.y *= inv; s.z *= inv; s.w *= inv;
        ((float4*)(out_y + (size_t)seg * DD))[tid] = s;
    }
}

// ============ K2: u = y @ M_w. y via wave-uniform (scalar) loads, TM=8 segs/block ============
__global__ __launch_bounds__(NT) void k_u(
    const float* __restrict__ y,      // [NSEG, D]
    const float* __restrict__ M_w,    // [D, D]
    float* __restrict__ u)            // [NSEG, D]
{
    const int tid  = threadIdx.x;
    const int row0 = blockIdx.x * TM;
    if (tid >= DD) return;            // no barriers below

    float acc[TM];
    #pragma unroll
    for (int r = 0; r < TM; ++r) acc[r] = 0.f;

    #pragma unroll 5
    for (int e = 0; e < DD; ++e) {
        const float m = M_w[(size_t)e * DD + tid];          // coalesced vector load
        #pragma unroll
        for (int r = 0; r < TM; ++r)
            acc[r] += m * y[(size_t)(row0 + r) * DD + e];   // uniform addr -> s_load
    }
    #pragma unroll
    for (int r = 0; r < TM; ++r)
        u[(size_t)(row0 + r) * DD + tid] = acc[r];
}

// ============ K3: fused stage+esc (f32), softmax, z from fp16 LDS rows, p, r ============
__global__ __launch_bounds__(NT) void k_rest(
    const float* __restrict__ emb,
    const float* __restrict__ W_w,    // [K, D]
    const float* __restrict__ T_w,    // [D, K]
    const int*   __restrict__ tokens,
    const int*   __restrict__ seg_starts,
    const int*   __restrict__ seg_lens,
    const float* __restrict__ u_ws,   // [NSEG, D]
    float* __restrict__ out_z,
    float* __restrict__ out_p,
    float* __restrict__ out_r)
{
    __shared__ int    tok_s[LL];
    __shared__ uint2  e_s[LL][75];    // 38.4 KB: fp16 rows (uint2 = 4 halfs = 4 d's)
    __shared__ float  a_s[LL + 1];    // scores -> alpha; a_s[64] = 0 sentinel
    __shared__ float2 zp_s[NW][150];  // 6 KB per-wave z partials
    __shared__ float  z_s[NT];
    __shared__ float  p_s[64];

    const int tid  = threadIdx.x;
    const int wave = tid >> 6;
    const int lane = tid & 63;
    const int seg  = blockIdx.x;
    const int b    = seg >> 7;
    const int start = seg_starts[seg];
    const int len   = seg_lens[seg];

    if (tid < LL) tok_s[tid] = tokens[b * SS + start + tid];
    __syncthreads();

    // ---- u in float4 lane layout (d = 4*lane..4*lane+3, + 256-chunk for lanes 0-10) ----
    float4 u0, u1 = {0.f, 0.f, 0.f, 0.f};
    {
        const float4* up4 = (const float4*)(u_ws + (size_t)seg * DD);
        u0 = up4[lane];
        if (lane < 11) u1 = up4[64 + lane];
    }

    // ---- stage rows to fp16 LDS + esc dot from f32 registers (fused) ----
    #pragma unroll
    for (int j = 0; j < NJ; ++j) {
        const int l  = wave + j * NW;
        const int lc = (l < len) ? l : (len - 1);
        const float4* row4 = (const float4*)(emb + (size_t)tok_s[lc] * DD);
        const float4 r0 = row4[lane];
        float4 r1 = {0.f, 0.f, 0.f, 0.f};
        if (lane < 11) r1 = row4[64 + lane];

        if (l < LL) {                  // wave-uniform (only wave 4, j=12 fails)
            e_s[l][lane] = make_uint2(pack_h2(r0.x, r0.y), pack_h2(r0.z, r0.w));
            if (lane < 11)
                e_s[l][64 + lane] = make_uint2(pack_h2(r1.x, r1.y), pack_h2(r1.z, r1.w));
        }

        float dot = r0.x * u0.x + r0.y * u0.y + r0.z * u0.z + r0.w * u0.w
                  + r1.x * u1.x + r1.y * u1.y + r1.z * u1.z + r1.w * u1.w;
        dot = wave_sum(dot);
        if (lane == 0 && l < len) a_s[l] = dot;
    }
    if (tid == NT - 1) a_s[LL] = 0.f;
    __syncthreads();

    // ---- softmax over rows (wave 0) ----
    if (wave == 0) {
        const float v  = (lane < len) ? a_s[lane] : -INFINITY;
        const float mx = wave_max(v);
        const float e  = (lane < len) ? __expf(v - mx) : 0.f;
        const float sm = wave_sum(e);
        a_s[lane] = e / sm;            // zeros for padded lanes
    }
    __syncthreads();

    // ---- z from fp16 LDS rows (alpha = 0 kills pad/clamped rows) ----
    {
        float2 zA = {0.f, 0.f}, zB = {0.f, 0.f}, zC = {0.f, 0.f};
        #pragma unroll
        for (int j = 0; j < NJ; ++j) {
            const int l  = wave + j * NW;
            const int lr = (l < LL) ? l : (LL - 1);
            const float a = a_s[l];    // a_s[64] = 0 sentinel
            const unsigned int* ru = (const unsigned int*)&e_s[lr][0];
            const float2 fA = unpack_h2(ru[lane]);
            const float2 fB = unpack_h2(ru[64 + lane]);
            zA.x += a * fA.x; zA.y += a * fA.y;
            zB.x += a * fB.x; zB.y += a * fB.y;
            if (lane < 22) {
                const float2 fC = unpack_h2(ru[128 + lane]);
                zC.x += a * fC.x; zC.y += a * fC.y;
            }
        }
        zp_s[wave][lane]      = zA;
        zp_s[wave][64 + lane] = zB;
        if (lane < 22) zp_s[wave][128 + lane] = zC;
    }
    __syncthreads();

    // ---- combine z partials; write out_z; z_s for p-phase ----
    if (tid < 150) {
        float2 s = {0.f, 0.f};
        #pragma unroll
        for (int w = 0; w < NW; ++w) {
            const float2 pv = zp_s[w][tid];
            s.x += pv.x; s.y += pv.y;
        }
        z_s[2 * tid]     = s.x;
        z_s[2 * tid + 1] = s.y;
        ((float2*)(out_z + (size_t)seg * DD))[tid] = s;
    }
    __syncthreads();

    // ---- topic scores: wave-per-k (10 per wave) ----
    for (int k = wave; k < KK; k += NW) {
        const float* wr = W_w + (size_t)k * DD;
        float d0 = wr[lane] * z_s[lane] + wr[lane + 64] * z_s[lane + 64]
                 + wr[lane + 128] * z_s[lane + 128] + wr[lane + 192] * z_s[lane + 192];
        if (lane < 44) d0 += wr[lane + 256] * z_s[lane + 256];
        d0 = wave_sum(d0);
        if (lane == 0) p_s[k] = d0;
    }
    __syncthreads();

    // ---- softmax over k (wave 0), write p ----
    if (wave == 0) {
        const float v  = (lane < KK) ? p_s[lane] : -INFINITY;
        const float mx = wave_max(v);
        const float e  = (lane < KK) ? __expf(v - mx) : 0.f;
        const float sm = wave_sum(e);
        if (lane < KK) {
            const float p = e / sm;
            p_s[lane] = p;
            out_p[(size_t)seg * KK + lane] = p;
        }
    }
    __syncthreads();

    // ---- r[d] = sum_k p[k] * T_w[d,k] ----
    if (tid < DD) {
        const float* trow = T_w + (size_t)tid * KK;
        float acc = 0.f;
        #pragma unroll
        for (int k = 0; k < KK; ++k) acc += p_s[k] * trow[k];
        out_r[(size_t)seg * DD + tid] = acc;
    }
}

extern "C" void kernel_launch(void* const* d_in, const int* in_sizes, int n_in,
                              void* d_out, int out_size, void* d_ws, size_t ws_size,
                              hipStream_t stream) {
    const float* emb        = (const float*)d_in[0];
    const float* M_w        = (const float*)d_in[1];
    const float* W_w        = (const float*)d_in[2];
    const float* T_w        = (const float*)d_in[3];
    const int*   tokens     = (const int*)d_in[4];
    const int*   seg_starts = (const int*)d_in[5];
    const int*   seg_lens   = (const int*)d_in[6];

    float* out   = (float*)d_out;
    float* out_y = out;                                    // [NSEG*D]
    float* out_z = out + (size_t)NSEG * DD;                // [NSEG*D]
    float* out_p = out + (size_t)2 * NSEG * DD;            // [NSEG*K]
    float* out_r = out + (size_t)2 * NSEG * DD + (size_t)NSEG * KK;

    float* u_ws = (float*)d_ws;                            // [NSEG*D] = 4.9 MB

    hipLaunchKernelGGL(k_y, dim3(NSEG), dim3(NT), 0, stream,
                       emb, tokens, seg_starts, seg_lens, out_y);
    hipLaunchKernelGGL(k_u, dim3(NSEG / TM), dim3(NT), 0, stream,
                       out_y, M_w, u_ws);
    hipLaunchKernelGGL(k_rest, dim3(NSEG), dim3(NT), 0, stream,
                       emb, W_w, T_w, tokens, seg_starts, seg_lens,
                       u_ws, out_z, out_p, out_r);
}

// Round 8
// 186.492 us; speedup vs baseline: 1.2032x; 1.2032x over previous
//
#include <hip/hip_runtime.h>
#include <hip/hip_fp16.h>

#define DD 300
#define KK 50
#define BB 32
#define SS 8192
#define NN 128
#define LL 64
#define NSEG (BB * NN)   // 4096
#define NW 5             // waves per block (k_y / k_rest)
#define NT 320           // threads per block
#define NJ 13            // rows per wave = ceil(64/5)
#define TM 8             // segments per k_u block
#define RS 151           // LDS row stride in u32 (302 halfs); gcd(151,32)=1 -> conflict-free

__device__ __forceinline__ float wave_sum(float v) {
    #pragma unroll
    for (int m = 32; m; m >>= 1) v += __shfl_xor(v, m, 64);
    return v;
}
__device__ __forceinline__ float wave_max(float v) {
    #pragma unroll
    for (int m = 32; m; m >>= 1) v = fmaxf(v, __shfl_xor(v, m, 64));
    return v;
}
__device__ __forceinline__ unsigned int pack_h2(float a, float b) {
    __half2 h = __floats2half2_rn(a, b);
    return *reinterpret_cast<const unsigned int*>(&h);
}
__device__ __forceinline__ float2 unpack_h2(unsigned int v) {
    __half2 h = *reinterpret_cast<const __half2*>(&v);
    return __half22float2(h);
}

// ============ K1: y = masked mean — branch-free overlapped float4 gather, burst loads ============
__global__ __launch_bounds__(NT) void k_y(
    const float* __restrict__ emb,
    const int*   __restrict__ tokens,
    const int*   __restrict__ seg_starts,
    const int*   __restrict__ seg_lens,
    float* __restrict__ out_y)
{
    __shared__ int    tok_s[LL];
    __shared__ float4 part4[NW][75];      // 6 KB

    const int tid  = threadIdx.x;
    const int wave = tid >> 6;
    const int lane = tid & 63;
    const int seg  = blockIdx.x;
    const int b    = seg >> 7;            // N = 128
    const int start = seg_starts[seg];
    const int len   = seg_lens[seg];

    if (tid < LL) tok_s[tid] = tokens[b * SS + start + tid];
    __syncthreads();

    // A covers floats 4*lane..4*lane+3 (0..255); B covers 44+4*lane.. (44..299).
    // Overlap region holds identical sums -> same-value write collisions are benign.
    float4 accA = {0.f, 0.f, 0.f, 0.f};
    float4 accB = {0.f, 0.f, 0.f, 0.f};
    #pragma unroll
    for (int jb = 0; jb < 2; ++jb) {
        const int j0 = jb * 7;
        const int j1 = (jb == 0) ? 7 : NJ;
        float4 A[7], B[7];
        #pragma unroll
        for (int j = j0; j < j1; ++j) {
            const int l  = wave + j * NW;
            const int lc = (l < len) ? l : (len - 1);
            const float4* row4 = (const float4*)(emb + (size_t)tok_s[lc] * DD);
            A[j - j0] = row4[lane];
            B[j - j0] = row4[11 + lane];
        }
        __builtin_amdgcn_sched_barrier(0);
        #pragma unroll
        for (int j = j0; j < j1; ++j) {
            const int l = wave + j * NW;
            const float m = (l < len) ? 1.f : 0.f;
            accA.x += m * A[j - j0].x; accA.y += m * A[j - j0].y;
            accA.z += m * A[j - j0].z; accA.w += m * A[j - j0].w;
            accB.x += m * B[j - j0].x; accB.y += m * B[j - j0].y;
            accB.z += m * B[j - j0].z; accB.w += m * B[j - j0].w;
        }
    }
    part4[wave][lane]      = accA;
    part4[wave][11 + lane] = accB;        // overlap 11..63 same-value with accA writes
    __syncthreads();

    if (tid < 75) {
        float4 s = {0.f, 0.f, 0.f, 0.f};
        #pragma unroll
        for (int w = 0; w < NW; ++w) {
            const float4 pv = part4[w][tid];
            s.x += pv.x; s.y += pv.y; s.z += pv.z; s.w += pv.w;
        }
        const float inv = 1.f / (float)len;
        s.x *= inv; s.y *= inv; s.z *= inv; s.w *= inv;
        ((float4*)(out_y + (size_t)seg * DD))[tid] = s;
    }
}

// ============ K2: u = y @ M_w. y via wave-uniform (scalar) loads, TM=8 segs/block ============
__global__ __launch_bounds__(NT) void k_u(
    const float* __restrict__ y,      // [NSEG, D]
    const float* __restrict__ M_w,    // [D, D]
    float* __restrict__ u)            // [NSEG, D]
{
    const int tid  = threadIdx.x;
    const int row0 = blockIdx.x * TM;
    if (tid >= DD) return;            // no barriers below

    float acc[TM];
    #pragma unroll
    for (int r = 0; r < TM; ++r) acc[r] = 0.f;

    #pragma unroll 5
    for (int e = 0; e < DD; ++e) {
        const float m = M_w[(size_t)e * DD + tid];          // coalesced vector load
        #pragma unroll
        for (int r = 0; r < TM; ++r)
            acc[r] += m * y[(size_t)(row0 + r) * DD + e];   // uniform addr -> s_load
    }
    #pragma unroll
    for (int r = 0; r < TM; ++r)
        u[(size_t)(row0 + r) * DD + tid] = acc[r];
}

// ============ K3: burst-stage fp16 rows -> per-lane-row esc -> softmax -> z -> p -> r ============
__global__ __launch_bounds__(NT) void k_rest(
    const float* __restrict__ emb,
    const float* __restrict__ W_w,    // [K, D]
    const float* __restrict__ T_w,    // [D, K]
    const int*   __restrict__ tokens,
    const int*   __restrict__ seg_starts,
    const int*   __restrict__ seg_lens,
    const float* __restrict__ u_ws,   // [NSEG, D]
    float* __restrict__ out_z,
    float* __restrict__ out_p,
    float* __restrict__ out_r)
{
    __shared__ unsigned int e16[LL * RS];   // 38.7 KB fp16 rows, stride 151 u32
    __shared__ int    tok_s[LL];
    __shared__ float  u_s[304];
    __shared__ float  pe_s[NW][LL];         // per-wave esc partials
    __shared__ float  a_s[LL + 1];          // alpha; a_s[64] = 0 sentinel
    __shared__ float2 zp_s[NW][150];        // per-wave z partials (6 KB)
    __shared__ float  z_s[NT];
    __shared__ float  p_s[64];

    const int tid  = threadIdx.x;
    const int wave = tid >> 6;
    const int lane = tid & 63;
    const int seg  = blockIdx.x;
    const int b    = seg >> 7;
    const int start = seg_starts[seg];
    const int len   = seg_lens[seg];

    if (tid < LL) tok_s[tid] = tokens[b * SS + start + tid];
    if (tid < 75) ((float4*)u_s)[tid] = ((const float4*)(u_ws + (size_t)seg * DD))[tid];
    __syncthreads();

    // ---- stage: branch-free overlapped loads in bursts; pack fp16 -> LDS ----
    // Data row index is CLAMPED (lc), but the LDS DESTINATION is the unclamped l
    // (guarded l < LL) so every one of the 64 LDS rows holds valid halfs.
    // Pad rows [len,64) duplicate row len-1's data; they are killed later by
    // alpha=0 (z phase) and lane<len masking (softmax). THIS is the r7 NaN fix.
    #pragma unroll
    for (int jb = 0; jb < 2; ++jb) {
        const int j0 = jb * 7;
        const int j1 = (jb == 0) ? 7 : NJ;
        float4 A[7], B[7];
        #pragma unroll
        for (int j = j0; j < j1; ++j) {
            const int l  = wave + j * NW;
            const int lc = (l < len) ? l : (len - 1);
            const float4* row4 = (const float4*)(emb + (size_t)tok_s[lc] * DD);
            A[j - j0] = row4[lane];
            B[j - j0] = row4[11 + lane];
        }
        __builtin_amdgcn_sched_barrier(0);
        #pragma unroll
        for (int j = j0; j < j1; ++j) {
            const int l = wave + j * NW;
            if (l < LL) {              // wave-uniform (only wave 4, j=12 fails)
                unsigned int* rw = &e16[l * RS];
                rw[2 * lane]      = pack_h2(A[j - j0].x, A[j - j0].y);
                rw[2 * lane + 1]  = pack_h2(A[j - j0].z, A[j - j0].w);
                rw[22 + 2 * lane] = pack_h2(B[j - j0].x, B[j - j0].y);
                rw[23 + 2 * lane] = pack_h2(B[j - j0].z, B[j - j0].w);
            }
        }
    }
    __syncthreads();

    // ---- esc partials: lane owns row `lane`; wave w covers u32 cols [30w, 30w+30) ----
    {
        const int c0 = 30 * wave;
        const unsigned int* myrow = &e16[lane * RS];
        float acc = 0.f;
        #pragma unroll
        for (int c = 0; c < 30; ++c) {
            const float2 ef = unpack_h2(myrow[c0 + c]);     // 2-way banked (stride 151)
            acc += ef.x * u_s[2 * (c0 + c)] + ef.y * u_s[2 * (c0 + c) + 1];  // LDS broadcast
        }
        pe_s[wave][lane] = acc;
    }
    if (tid == NT - 1) a_s[LL] = 0.f;
    __syncthreads();

    // ---- combine esc + softmax, all in-lane (wave 0; lane = row) ----
    if (wave == 0) {
        const float esc = pe_s[0][lane] + pe_s[1][lane] + pe_s[2][lane]
                        + pe_s[3][lane] + pe_s[4][lane];
        const float v  = (lane < len) ? esc : -INFINITY;
        const float mx = wave_max(v);
        const float e  = (lane < len) ? __expf(v - mx) : 0.f;
        const float sm = wave_sum(e);
        a_s[lane] = e / sm;            // zeros for padded lanes
    }
    __syncthreads();

    // ---- z from fp16 LDS rows (alpha = 0 kills pad rows) ----
    {
        float2 zA = {0.f, 0.f}, zB = {0.f, 0.f}, zC = {0.f, 0.f};
        #pragma unroll
        for (int j = 0; j < NJ; ++j) {
            const int l  = wave + j * NW;
            const int lr = (l < LL) ? l : (LL - 1);
            const float a = a_s[l];    // a_s[64] = 0 sentinel
            const unsigned int* ru = &e16[lr * RS];
            const float2 fA = unpack_h2(ru[lane]);
            const float2 fB = unpack_h2(ru[64 + lane]);
            zA.x += a * fA.x; zA.y += a * fA.y;
            zB.x += a * fB.x; zB.y += a * fB.y;
            if (lane < 22) {
                const float2 fC = unpack_h2(ru[128 + lane]);
                zC.x += a * fC.x; zC.y += a * fC.y;
            }
        }
        zp_s[wave][lane]      = zA;
        zp_s[wave][64 + lane] = zB;
        if (lane < 22) zp_s[wave][128 + lane] = zC;
    }
    __syncthreads();

    // ---- combine z partials; write out_z; z_s for p-phase ----
    if (tid < 150) {
        float2 s = {0.f, 0.f};
        #pragma unroll
        for (int w = 0; w < NW; ++w) {
            const float2 pv = zp_s[w][tid];
            s.x += pv.x; s.y += pv.y;
        }
        z_s[2 * tid]     = s.x;
        z_s[2 * tid + 1] = s.y;
        ((float2*)(out_z + (size_t)seg * DD))[tid] = s;
    }
    __syncthreads();

    // ---- topic scores: wave-per-k (10 per wave) ----
    for (int k = wave; k < KK; k += NW) {
        const float* wr = W_w + (size_t)k * DD;
        float d0 = wr[lane] * z_s[lane] + wr[lane + 64] * z_s[lane + 64]
                 + wr[lane + 128] * z_s[lane + 128] + wr[lane + 192] * z_s[lane + 192];
        if (lane < 44) d0 += wr[lane + 256] * z_s[lane + 256];
        d0 = wave_sum(d0);
        if (lane == 0) p_s[k] = d0;
    }
    __syncthreads();

    // ---- softmax over k (wave 0), write p ----
    if (wave == 0) {
        const float v  = (lane < KK) ? p_s[lane] : -INFINITY;
        const float mx = wave_max(v);
        const float e  = (lane < KK) ? __expf(v - mx) : 0.f;
        const float sm = wave_sum(e);
        if (lane < KK) {
            const float p = e / sm;
            p_s[lane] = p;
            out_p[(size_t)seg * KK + lane] = p;
        }
    }
    __syncthreads();

    // ---- r[d] = sum_k p[k] * T_w[d,k] ----
    if (tid < DD) {
        const float* trow = T_w + (size_t)tid * KK;
        float acc = 0.f;
        #pragma unroll
        for (int k = 0; k < KK; ++k) acc += p_s[k] * trow[k];
        out_r[(size_t)seg * DD + tid] = acc;
    }
}

extern "C" void kernel_launch(void* const* d_in, const int* in_sizes, int n_in,
                              void* d_out, int out_size, void* d_ws, size_t ws_size,
                              hipStream_t stream) {
    const float* emb        = (const float*)d_in[0];
    const float* M_w        = (const float*)d_in[1];
    const float* W_w        = (const float*)d_in[2];
    const float* T_w        = (const float*)d_in[3];
    const int*   tokens     = (const int*)d_in[4];
    const int*   seg_starts = (const int*)d_in[5];
    const int*   seg_lens   = (const int*)d_in[6];

    float* out   = (float*)d_out;
    float* out_y = out;                                    // [NSEG*D]
    float* out_z = out + (size_t)NSEG * DD;                // [NSEG*D]
    float* out_p = out + (size_t)2 * NSEG * DD;            // [NSEG*K]
    float* out_r = out + (size_t)2 * NSEG * DD + (size_t)NSEG * KK;

    float* u_ws = (float*)d_ws;                            // [NSEG*D] = 4.9 MB

    hipLaunchKernelGGL(k_y, dim3(NSEG), dim3(NT), 0, stream,
                       emb, tokens, seg_starts, seg_lens, out_y);
    hipLaunchKernelGGL(k_u, dim3(NSEG / TM), dim3(NT), 0, stream,
                       out_y, M_w, u_ws);
    hipLaunchKernelGGL(k_rest, dim3(NSEG), dim3(NT), 0, stream,
                       emb, W_w, T_w, tokens, seg_starts, seg_lens,
                       u_ws, out_z, out_p, out_r);
}